// Round 9
// baseline (254.016 us; speedup 1.0000x reference)
//
#include <hip/hip_runtime.h>

typedef unsigned short u16;
typedef _Float16 half8 __attribute__((ext_vector_type(8)));
typedef _Float16 h2 __attribute__((ext_vector_type(2)));
typedef float f32x4 __attribute__((ext_vector_type(4)));
typedef u16 u16x4 __attribute__((ext_vector_type(4)));
typedef u16 u16x8 __attribute__((ext_vector_type(8)));

#define MFMAH(a, b, c) __builtin_amdgcn_mfma_f32_16x16x32_f16(a, b, c, 0, 0, 0)

constexpr float LOG2E = 1.44269504088896f;
constexpr float THR = 12.0f;  // defer-max threshold in log2 units (p <= 2^12, fp16-safe)

// f32 -> fp16 RNE
__device__ __forceinline__ u16 f2h(float f) {
  _Float16 h = (_Float16)f;
  return __builtin_bit_cast(u16, h);
}
// packed f32x2 -> fp16x2 (RTZ)
__device__ __forceinline__ h2 pkrtz(float a, float b) {
  return __builtin_bit_cast(h2, __builtin_amdgcn_cvt_pkrtz(a, b));
}

__device__ __forceinline__ void gload_lds16(const void* g, void* l) {
  __builtin_amdgcn_global_load_lds(
      (const __attribute__((address_space(1))) void*)g,
      (__attribute__((address_space(3))) void*)l,
      16, 0, 0);
}

// ---------------- fp32 -> fp16 conversion (weights only now) ----------------
__device__ __forceinline__ void conv_block(const float* __restrict__ in,
                                           u16* __restrict__ out, int i) {
  const float4 a = reinterpret_cast<const float4*>(in)[2 * i];
  const float4 b = reinterpret_cast<const float4*>(in)[2 * i + 1];
  u16x8 o;
  o[0] = f2h(a.x); o[1] = f2h(a.y); o[2] = f2h(a.z); o[3] = f2h(a.w);
  o[4] = f2h(b.x); o[5] = f2h(b.y); o[6] = f2h(b.z); o[7] = f2h(b.w);
  reinterpret_cast<u16x8*>(out)[i] = o;
}

__global__ __launch_bounds__(256) void conv_w4(const float* __restrict__ w0,
                                               const float* __restrict__ w1,
                                               const float* __restrict__ w2,
                                               const float* __restrict__ w3,
                                               u16* __restrict__ o0, u16* __restrict__ o1,
                                               u16* __restrict__ o2, u16* __restrict__ o3,
                                               int n8) {
  int i = blockIdx.x * 256 + threadIdx.x;
  const int stride = gridDim.x * 256;
  for (; i < 4 * n8; i += stride) {
    const int sel = i / n8, j = i - sel * n8;
    if (sel == 0) conv_block(w0, o0, j);
    else if (sel == 1) conv_block(w1, o1, j);
    else if (sel == 2) conv_block(w2, o2, j);
    else conv_block(w3, o3, j);
  }
}

// ---------------- GEMM: C[m,n] = (sum_k A[m,k]*Bw[n,k] + bias[n]) * scale ----------------
// A32=true: A is FLOAT32 row-major; staged via regs + cvt_pkrtz + ds_write (fuses the
//           f32->fp16 conversion into the GEMM, eliminating the conv pass).
// A32=false: A is fp16, staged via global_load_lds.
// MODE 0: C row-major [M,N] FLOAT32 (final output buffer) + loss scalar at [M*N]
// MODE 1: C as [B,H,S,D] fp16 (m = b*2048+s, n = h*64+d); scale=log2e for Q
// MODE 2: C in swizzled PV-fragment order fp16 (see attn_fwd V-read)
template <int MODE, bool A32>
__global__ __launch_bounds__(256) void gemm_bt(const void* __restrict__ Av,
                                               const u16* __restrict__ Bw,
                                               const float* __restrict__ bias,
                                               void* __restrict__ Cv,
                                               int M, int N, int K, float scale) {
  __shared__ u16 As[128 * 32];
  __shared__ u16 Bs[128 * 32];
  const int tid = threadIdx.x;
  const int lane = tid & 63;
  const int l16 = lane & 15, lhi = lane >> 4;
  const int wid = tid >> 6;
  const int wm = wid >> 1, wn = wid & 1;
  const int bm0 = blockIdx.y * 128;
  const int bn0 = blockIdx.x * 128;

  const int c0 = tid, c1 = tid + 256;
  const u16* A16 = (const u16*)Av;
  const float* Af = (const float*)Av;
  const u16* Ag0 = A16 + (size_t)(bm0 + (c0 >> 2)) * K + (c0 & 3) * 8;
  const u16* Ag1 = A16 + (size_t)(bm0 + (c1 >> 2)) * K + (c1 & 3) * 8;
  const u16* Bg0 = Bw + (size_t)(bn0 + (c0 >> 2)) * K + (c0 & 3) * 8;
  const u16* Bg1 = Bw + (size_t)(bn0 + (c1 >> 2)) * K + (c1 & 3) * 8;
  // A32 reg-staging: thread owns row tid>>1, 16-col half tid&1
  const float* Ar = Af + (size_t)(bm0 + (tid >> 1)) * K + (tid & 1) * 16;
  u16* AsW = &As[(tid >> 1) * 32 + (tid & 1) * 16];

  f32x4 acc[4][4] = {};

  for (int kt = 0; kt < K; kt += 32) {
    if constexpr (A32) {
      const float4 a0 = *reinterpret_cast<const float4*>(Ar + kt);
      const float4 a1 = *reinterpret_cast<const float4*>(Ar + kt + 4);
      const float4 a2 = *reinterpret_cast<const float4*>(Ar + kt + 8);
      const float4 a3 = *reinterpret_cast<const float4*>(Ar + kt + 12);
      gload_lds16(Bg0 + kt, &Bs[c0 * 8]);
      gload_lds16(Bg1 + kt, &Bs[c1 * 8]);
      union { u16x8 u; h2 h[4]; } w0, w1;
      w0.h[0] = pkrtz(a0.x, a0.y); w0.h[1] = pkrtz(a0.z, a0.w);
      w0.h[2] = pkrtz(a1.x, a1.y); w0.h[3] = pkrtz(a1.z, a1.w);
      w1.h[0] = pkrtz(a2.x, a2.y); w1.h[1] = pkrtz(a2.z, a2.w);
      w1.h[2] = pkrtz(a3.x, a3.y); w1.h[3] = pkrtz(a3.z, a3.w);
      *reinterpret_cast<u16x8*>(AsW) = w0.u;
      *reinterpret_cast<u16x8*>(AsW + 8) = w1.u;
    } else {
      gload_lds16(Ag0 + kt, &As[c0 * 8]);
      gload_lds16(Ag1 + kt, &As[c1 * 8]);
      gload_lds16(Bg0 + kt, &Bs[c0 * 8]);
      gload_lds16(Bg1 + kt, &Bs[c1 * 8]);
    }
    __syncthreads();
    half8 af[4], bf[4];
#pragma unroll
    for (int f = 0; f < 4; ++f)
      af[f] = *reinterpret_cast<const half8*>(&As[(wm * 64 + f * 16 + l16) * 32 + lhi * 8]);
#pragma unroll
    for (int f = 0; f < 4; ++f)
      bf[f] = *reinterpret_cast<const half8*>(&Bs[(wn * 64 + f * 16 + l16) * 32 + lhi * 8]);
#pragma unroll
    for (int i = 0; i < 4; ++i)
#pragma unroll
      for (int j = 0; j < 4; ++j)
        acc[i][j] = MFMAH(af[i], bf[j], acc[i][j]);
    __syncthreads();
  }

#pragma unroll
  for (int i = 0; i < 4; ++i) {
    const int m0 = bm0 + wm * 64 + i * 16 + lhi * 4;
#pragma unroll
    for (int j = 0; j < 4; ++j) {
      const int n = bn0 + wn * 64 + j * 16 + l16;
      const float bb = bias[n];
      if (MODE == 0) {
        float* Cf = (float*)Cv;
#pragma unroll
        for (int r = 0; r < 4; ++r)
          Cf[(size_t)(m0 + r) * N + n] = acc[i][j][r] + bb;
      } else if (MODE == 2) {
        u16* C = (u16*)Cv;
        u16x4 pack;
#pragma unroll
        for (int r = 0; r < 4; ++r) pack[r] = f2h(acc[i][j][r] + bb);
        const int head = (m0 >> 11) * 16 + (n >> 6);
        const int s0 = m0 & 2047;
        const int d = n & 63;
        const int within =
            ((s0 >> 5) & 1) * 2048 + d * 32 + ((s0 >> 2) & 3) * 8 + ((s0 >> 4) & 1) * 4;
        const int sw = within ^ ((d & 7) << 3);  // bank swizzle (matches attn read)
        const size_t idx = (size_t)head * 131072 + (size_t)(s0 >> 6) * 4096 + sw;
        *reinterpret_cast<u16x4*>(&C[idx]) = pack;
      } else {
        u16* C = (u16*)Cv;
#pragma unroll
        for (int r = 0; r < 4; ++r) {
          const int m = m0 + r;
          const size_t idx =
              ((size_t)((m >> 11) * 16 + (n >> 6)) * 2048 + (m & 2047)) * 64 + (n & 63);
          C[idx] = f2h((acc[i][j][r] + bb) * scale);
        }
      }
    }
  }
  if (MODE == 0) {
    if (blockIdx.x == 0 && blockIdx.y == 0 && tid == 0)
      ((float*)Cv)[(size_t)M * N] = 0.0f;  // loss scalar
  }
}

// ---------------- Flash attention: LDS-staged K/V, 2-phase pipeline, XCD swizzle --------
// Q,K: [B,H,S,D] fp16 (Q pre-scaled by log2e); VL: swizzled fragment-order V;
// X: [B,S,H*D] fp16. 1024 blocks, 4 waves each (32 q-rows/wave).
__global__ __launch_bounds__(256, 4) void attn_fwd(const u16* __restrict__ Q,
                                                   const u16* __restrict__ Kh,
                                                   const u16* __restrict__ VL,
                                                   u16* __restrict__ X) {
  __shared__ u16 Ks[2][4096];  // 64 keys x 64 d (swizzled)
  __shared__ u16 Vs[2][4096];  // 2 fragment-order sub-blocks (32 keys each, swizzled)

  const int tid = threadIdx.x, lane = tid & 63, w = tid >> 6;
  const int l16 = lane & 15, lhi = lane >> 4;
  // XCD-aware decomposition: each XCD gets 8 consecutive heads (K/V L2-resident)
  const int blk = blockIdx.x;
  const int xcd = blk & 7, wi = blk >> 3;
  const int bh = (xcd << 3) | (wi >> 4);
  const int qt = wi & 15;
  const int b = bh >> 4, h = bh & 15;

  const size_t qrow0 = (size_t)bh * 2048 + qt * 128 + w * 32;
  half8 qf[2][2];
#pragma unroll
  for (int fq = 0; fq < 2; ++fq)
#pragma unroll
    for (int ks = 0; ks < 2; ++ks)
      qf[fq][ks] = *reinterpret_cast<const half8*>(
          &Q[(qrow0 + fq * 16 + l16) * 64 + ks * 32 + lhi * 8]);

  f32x4 o[2][4] = {};
  float mrow[2] = {-1e30f, -1e30f};
  float ssum[2] = {0.0f, 0.0f};

  const u16* Kb = Kh + (size_t)bh * 2048 * 64;
  const u16* VLh = VL + (size_t)bh * 64 * 64 * 32;

#define STAGE_KV(bufidx, tt)                                                      \
  do {                                                                            \
    const int kb0_ = (tt) * 64;                                                   \
    _Pragma("unroll")                                                             \
    for (int ii_ = 0; ii_ < 2; ++ii_) {                                           \
      const int c_ = tid + ii_ * 256;                                             \
      const int r_ = c_ >> 3, cb_ = c_ & 7;                                       \
      gload_lds16(Kb + (size_t)(kb0_ + r_) * 64 + ((cb_ ^ (r_ & 7)) << 3),        \
                  &Ks[bufidx][c_ * 8]);                                           \
      gload_lds16(VLh + (size_t)(tt) * 4096 + c_ * 8, &Vs[bufidx][c_ * 8]);       \
    }                                                                             \
  } while (0)

  STAGE_KV(0, 0);
  __syncthreads();

  for (int t = 0; t < 32; ++t) {
    const int cur = t & 1;
    if (t < 31) STAGE_KV(cur ^ 1, t + 1);  // issue next-tile loads BEFORE compute
    // ---- QK^T from swizzled K in LDS (rows=keys, cols=q) ----
    f32x4 sc[2][4] = {};
    __builtin_amdgcn_s_setprio(1);
#pragma unroll
    for (int fk = 0; fk < 4; ++fk) {
      const int row = fk * 16 + l16;
#pragma unroll
      for (int ks = 0; ks < 2; ++ks) {
        const int off = (row * 64 + ks * 32 + lhi * 8) ^ ((row & 7) << 3);
        const half8 kf = *reinterpret_cast<const half8*>(&Ks[cur][off]);
#pragma unroll
        for (int fq = 0; fq < 2; ++fq) sc[fq][fk] = MFMAH(kf, qf[fq][ks], sc[fq][fk]);
      }
    }
    __builtin_amdgcn_s_setprio(0);
    // ---- defer-max online softmax (no cross-lane in common path) ----
    float lm[2];
#pragma unroll
    for (int fq = 0; fq < 2; ++fq) {
      float a0 = fmaxf(fmaxf(sc[fq][0][0], sc[fq][0][1]), sc[fq][0][2]);
      float a1 = fmaxf(fmaxf(sc[fq][0][3], sc[fq][1][0]), sc[fq][1][1]);
      float a2 = fmaxf(fmaxf(sc[fq][1][2], sc[fq][1][3]), sc[fq][2][0]);
      float a3 = fmaxf(fmaxf(sc[fq][2][1], sc[fq][2][2]), sc[fq][2][3]);
      float a4 = fmaxf(fmaxf(sc[fq][3][0], sc[fq][3][1]), sc[fq][3][2]);
      float b0 = fmaxf(fmaxf(a0, a1), a2);
      float b1 = fmaxf(fmaxf(a3, a4), sc[fq][3][3]);
      lm[fq] = fmaxf(b0, b1);
    }
    const int trig = (lm[0] > mrow[0] + THR) || (lm[1] > mrow[1] + THR);
    if (__any(trig)) {
#pragma unroll
      for (int fq = 0; fq < 2; ++fq) {
        float rm = lm[fq];
        rm = fmaxf(rm, __shfl_xor(rm, 16));
        rm = fmaxf(rm, __shfl_xor(rm, 32));
        const float nm = fmaxf(mrow[fq], rm);
        const float scl = __builtin_amdgcn_exp2f(mrow[fq] - nm);
        mrow[fq] = nm;
        ssum[fq] *= scl;
        float sb[4];
#pragma unroll
        for (int r = 0; r < 4; ++r) sb[r] = __shfl(scl, lhi * 4 + r);
#pragma unroll
        for (int fd = 0; fd < 4; ++fd)
#pragma unroll
          for (int r = 0; r < 4; ++r) o[fq][fd][r] *= sb[r];
      }
    }
    // ---- exp2 + pack P to fp16 ----
    half8 pa2[2][2];
#pragma unroll
    for (int fq = 0; fq < 2; ++fq) {
      union { half8 v[2]; h2 hh[8]; } uu;
#pragma unroll
      for (int fk = 0; fk < 4; ++fk) {
        const float p0 = __builtin_amdgcn_exp2f(sc[fq][fk][0] - mrow[fq]);
        const float p1 = __builtin_amdgcn_exp2f(sc[fq][fk][1] - mrow[fq]);
        const float p2 = __builtin_amdgcn_exp2f(sc[fq][fk][2] - mrow[fq]);
        const float p3 = __builtin_amdgcn_exp2f(sc[fq][fk][3] - mrow[fq]);
        ssum[fq] += (p0 + p1) + (p2 + p3);
        uu.hh[fk * 2 + 0] = pkrtz(p0, p1);
        uu.hh[fk * 2 + 1] = pkrtz(p2, p3);
      }
      pa2[fq][0] = uu.v[0];
      pa2[fq][1] = uu.v[1];
    }
    // ---- PV from swizzled fragment-order V in LDS ----
    __builtin_amdgcn_s_setprio(1);
#pragma unroll
    for (int fd = 0; fd < 4; ++fd)
#pragma unroll
      for (int ts = 0; ts < 2; ++ts) {
        const int va = (ts * 2048 + (fd * 16 + l16) * 32 + lhi * 8) ^ ((l16 & 7) << 3);
        const half8 vf = *reinterpret_cast<const half8*>(&Vs[cur][va]);
#pragma unroll
        for (int fq = 0; fq < 2; ++fq) o[fq][fd] = MFMAH(pa2[fq][ts], vf, o[fq][fd]);
      }
    __builtin_amdgcn_s_setprio(0);
    __syncthreads();  // drains vmcnt for next tile's stage; releases buffers
  }
#undef STAGE_KV

  // epilogue: reduce ssum across the 4 lanes of each row, normalize, store
#pragma unroll
  for (int fq = 0; fq < 2; ++fq) {
    float ss = ssum[fq];
    ss += __shfl_xor(ss, 16);
    ss += __shfl_xor(ss, 32);
    float iv[4];
#pragma unroll
    for (int r = 0; r < 4; ++r) iv[r] = 1.0f / __shfl(ss, lhi * 4 + r);
#pragma unroll
    for (int r = 0; r < 4; ++r) {
      const int q = qt * 128 + w * 32 + fq * 16 + lhi * 4 + r;
#pragma unroll
      for (int fd = 0; fd < 4; ++fd) {
        const int col = h * 64 + fd * 16 + l16;
        X[((size_t)b * 2048 + q) * 1024 + col] = f2h(o[fq][fd][r] * iv[r]);
      }
    }
  }
}

// ---------------- launch ----------------
extern "C" void kernel_launch(void* const* d_in, const int* in_sizes, int n_in,
                              void* d_out, int out_size, void* d_ws, size_t ws_size,
                              hipStream_t stream) {
  const float* q_f  = (const float*)d_in[0];
  const float* k_f  = (const float*)d_in[1];
  const float* v_f  = (const float*)d_in[2];
  const float* Wq_f = (const float*)d_in[4];
  const float* bq   = (const float*)d_in[5];
  const float* Wk_f = (const float*)d_in[6];
  const float* bk   = (const float*)d_in[7];
  const float* Wv_f = (const float*)d_in[8];
  const float* bv   = (const float*)d_in[9];
  const float* Wo_f = (const float*)d_in[10];
  const float* bo   = (const float*)d_in[11];

  const int SZ = 4 * 2048 * 1024;  // 8388608
  const int SW = 1024 * 1024;      // 1048576

  u16* ws = (u16*)d_ws;
  u16* wqb = ws;                 // fp16 weights
  u16* wkb = wqb + SW;
  u16* wvb = wkb + SW;
  u16* wob = wvb + SW;
  u16* Qb  = wob + SW;           // [B,H,S,D], pre-scaled by log2e
  u16* Kb  = Qb + SZ;            // [B,H,S,D]
  u16* VLb = Kb + SZ;            // swizzled fragment-order V
  u16* Xb  = VLb + SZ;           // [B,S,H*D]
  const size_t need_bytes = (size_t)(4 * SZ + 4 * SW) * 2;
  if (ws_size < need_bytes) return;

  conv_w4<<<1024, 256, 0, stream>>>(Wq_f, Wk_f, Wv_f, Wo_f, wqb, wkb, wvb, wob, SW / 8);

  dim3 gg(1024 / 128, 8192 / 128);
  gemm_bt<1, true><<<gg, 256, 0, stream>>>(q_f, wqb, bq, Qb, 8192, 1024, 1024, LOG2E);
  gemm_bt<1, true><<<gg, 256, 0, stream>>>(k_f, wkb, bk, Kb, 8192, 1024, 1024, 1.0f);
  gemm_bt<2, true><<<gg, 256, 0, stream>>>(v_f, wvb, bv, VLb, 8192, 1024, 1024, 1.0f);

  attn_fwd<<<dim3(1024), 256, 0, stream>>>(Qb, Kb, VLb, Xb);

  gemm_bt<0, false><<<gg, 256, 0, stream>>>(Xb, wob, bo, d_out, 8192, 1024, 1024, 1.0f);
}

// Round 10
// 244.479 us; speedup vs baseline: 1.0390x; 1.0390x over previous
//
#include <hip/hip_runtime.h>

typedef unsigned short u16;
typedef _Float16 half8 __attribute__((ext_vector_type(8)));
typedef _Float16 h2 __attribute__((ext_vector_type(2)));
typedef float f32x4 __attribute__((ext_vector_type(4)));
typedef u16 u16x4 __attribute__((ext_vector_type(4)));
typedef u16 u16x8 __attribute__((ext_vector_type(8)));

#define MFMAH(a, b, c) __builtin_amdgcn_mfma_f32_16x16x32_f16(a, b, c, 0, 0, 0)

constexpr float LOG2E = 1.44269504088896f;
constexpr float THR = 12.0f;  // defer-max threshold in log2 units (p <= 2^12, fp16-safe)

// f32 -> fp16 RNE
__device__ __forceinline__ u16 f2h(float f) {
  _Float16 h = (_Float16)f;
  return __builtin_bit_cast(u16, h);
}
// packed f32x2 -> fp16x2 (RTZ)
__device__ __forceinline__ h2 pkrtz(float a, float b) {
  return __builtin_bit_cast(h2, __builtin_amdgcn_cvt_pkrtz(a, b));
}

__device__ __forceinline__ void gload_lds16(const void* g, void* l) {
  __builtin_amdgcn_global_load_lds(
      (const __attribute__((address_space(1))) void*)g,
      (__attribute__((address_space(3))) void*)l,
      16, 0, 0);
}

// ---------------- fp32 -> fp16 conversion (weights only) ----------------
__device__ __forceinline__ void conv_block(const float* __restrict__ in,
                                           u16* __restrict__ out, int i) {
  const float4 a = reinterpret_cast<const float4*>(in)[2 * i];
  const float4 b = reinterpret_cast<const float4*>(in)[2 * i + 1];
  u16x8 o;
  o[0] = f2h(a.x); o[1] = f2h(a.y); o[2] = f2h(a.z); o[3] = f2h(a.w);
  o[4] = f2h(b.x); o[5] = f2h(b.y); o[6] = f2h(b.z); o[7] = f2h(b.w);
  reinterpret_cast<u16x8*>(out)[i] = o;
}

__global__ __launch_bounds__(256) void conv_w4(const float* __restrict__ w0,
                                               const float* __restrict__ w1,
                                               const float* __restrict__ w2,
                                               const float* __restrict__ w3,
                                               u16* __restrict__ o0, u16* __restrict__ o1,
                                               u16* __restrict__ o2, u16* __restrict__ o3,
                                               int n8) {
  int i = blockIdx.x * 256 + threadIdx.x;
  const int stride = gridDim.x * 256;
  for (; i < 4 * n8; i += stride) {
    const int sel = i / n8, j = i - sel * n8;
    if (sel == 0) conv_block(w0, o0, j);
    else if (sel == 1) conv_block(w1, o1, j);
    else if (sel == 2) conv_block(w2, o2, j);
    else conv_block(w3, o3, j);
  }
}

// ---------------- GEMM: C[m,n] = (sum_k A[m,k]*Bw[n,k] + bias[n]) * scale ----------------
// Block-id remap (T1): all 8 bn-blocks of one A-row-panel land on the SAME XCD so the
// panel is fetched once into that XCD's L2 (id%8 = XCD assumption, guide §1).
// A32=true: A is FLOAT32 row-major, reg-staged + cvt_pkrtz + ds_write (fused conversion).
// MODE 0: C row-major [M,N] FLOAT32 (+ loss scalar at [M*N])
// MODE 1: C as [B,H,S,D] fp16; scale=log2e for Q
// MODE 2: C in swizzled PV-fragment order fp16 (see attn_fwd V-read)
template <int MODE, bool A32>
__global__ __launch_bounds__(256) void gemm_bt(const void* __restrict__ Av,
                                               const u16* __restrict__ Bw,
                                               const float* __restrict__ bias,
                                               void* __restrict__ Cv,
                                               int M, int N, int K, float scale) {
  __shared__ u16 As[128 * 32];
  __shared__ u16 Bs[128 * 32];
  const int tid = threadIdx.x;
  const int lane = tid & 63;
  const int l16 = lane & 15, lhi = lane >> 4;
  const int wid = tid >> 6;
  const int wm = wid >> 1, wn = wid & 1;
  // XCD-colocating remap: xcd = id%8 stays, but all bx of one by share it.
  const int id = blockIdx.x + blockIdx.y * gridDim.x;
  const int xcd = id & 7, slot = id >> 3;
  const int by = ((slot & 7) << 3) | xcd;   // by % 8 == xcd
  const int bx = slot >> 3;
  const int bm0 = by * 128;
  const int bn0 = bx * 128;

  const int c0 = tid, c1 = tid + 256;
  const u16* A16 = (const u16*)Av;
  const float* Af = (const float*)Av;
  const u16* Ag0 = A16 + (size_t)(bm0 + (c0 >> 2)) * K + (c0 & 3) * 8;
  const u16* Ag1 = A16 + (size_t)(bm0 + (c1 >> 2)) * K + (c1 & 3) * 8;
  const u16* Bg0 = Bw + (size_t)(bn0 + (c0 >> 2)) * K + (c0 & 3) * 8;
  const u16* Bg1 = Bw + (size_t)(bn0 + (c1 >> 2)) * K + (c1 & 3) * 8;
  // A32 reg-staging: thread owns row tid>>1, 16-col half tid&1
  const float* Ar = Af + (size_t)(bm0 + (tid >> 1)) * K + (tid & 1) * 16;
  u16* AsW = &As[(tid >> 1) * 32 + (tid & 1) * 16];

  f32x4 acc[4][4] = {};

  for (int kt = 0; kt < K; kt += 32) {
    if constexpr (A32) {
      const float4 a0 = *reinterpret_cast<const float4*>(Ar + kt);
      const float4 a1 = *reinterpret_cast<const float4*>(Ar + kt + 4);
      const float4 a2 = *reinterpret_cast<const float4*>(Ar + kt + 8);
      const float4 a3 = *reinterpret_cast<const float4*>(Ar + kt + 12);
      gload_lds16(Bg0 + kt, &Bs[c0 * 8]);
      gload_lds16(Bg1 + kt, &Bs[c1 * 8]);
      union { u16x8 u; h2 h[4]; } w0, w1;
      w0.h[0] = pkrtz(a0.x, a0.y); w0.h[1] = pkrtz(a0.z, a0.w);
      w0.h[2] = pkrtz(a1.x, a1.y); w0.h[3] = pkrtz(a1.z, a1.w);
      w1.h[0] = pkrtz(a2.x, a2.y); w1.h[1] = pkrtz(a2.z, a2.w);
      w1.h[2] = pkrtz(a3.x, a3.y); w1.h[3] = pkrtz(a3.z, a3.w);
      *reinterpret_cast<u16x8*>(AsW) = w0.u;
      *reinterpret_cast<u16x8*>(AsW + 8) = w1.u;
    } else {
      gload_lds16(Ag0 + kt, &As[c0 * 8]);
      gload_lds16(Ag1 + kt, &As[c1 * 8]);
      gload_lds16(Bg0 + kt, &Bs[c0 * 8]);
      gload_lds16(Bg1 + kt, &Bs[c1 * 8]);
    }
    __syncthreads();
    half8 af[4], bf[4];
#pragma unroll
    for (int f = 0; f < 4; ++f)
      af[f] = *reinterpret_cast<const half8*>(&As[(wm * 64 + f * 16 + l16) * 32 + lhi * 8]);
#pragma unroll
    for (int f = 0; f < 4; ++f)
      bf[f] = *reinterpret_cast<const half8*>(&Bs[(wn * 64 + f * 16 + l16) * 32 + lhi * 8]);
#pragma unroll
    for (int i = 0; i < 4; ++i)
#pragma unroll
      for (int j = 0; j < 4; ++j)
        acc[i][j] = MFMAH(af[i], bf[j], acc[i][j]);
    __syncthreads();
  }

#pragma unroll
  for (int i = 0; i < 4; ++i) {
    const int m0 = bm0 + wm * 64 + i * 16 + lhi * 4;
#pragma unroll
    for (int j = 0; j < 4; ++j) {
      const int n = bn0 + wn * 64 + j * 16 + l16;
      const float bb = bias[n];
      if (MODE == 0) {
        float* Cf = (float*)Cv;
#pragma unroll
        for (int r = 0; r < 4; ++r)
          Cf[(size_t)(m0 + r) * N + n] = acc[i][j][r] + bb;
      } else if (MODE == 2) {
        u16* C = (u16*)Cv;
        u16x4 pack;
#pragma unroll
        for (int r = 0; r < 4; ++r) pack[r] = f2h(acc[i][j][r] + bb);
        const int head = (m0 >> 11) * 16 + (n >> 6);
        const int s0 = m0 & 2047;
        const int d = n & 63;
        const int within =
            ((s0 >> 5) & 1) * 2048 + d * 32 + ((s0 >> 2) & 3) * 8 + ((s0 >> 4) & 1) * 4;
        const int sw = within ^ ((d & 7) << 3);  // bank swizzle (matches attn read)
        const size_t idx = (size_t)head * 131072 + (size_t)(s0 >> 6) * 4096 + sw;
        *reinterpret_cast<u16x4*>(&C[idx]) = pack;
      } else {
        u16* C = (u16*)Cv;
#pragma unroll
        for (int r = 0; r < 4; ++r) {
          const int m = m0 + r;
          const size_t idx =
              ((size_t)((m >> 11) * 16 + (n >> 6)) * 2048 + (m & 2047)) * 64 + (n & 63);
          C[idx] = f2h((acc[i][j][r] + bb) * scale);
        }
      }
    }
  }
  if (MODE == 0) {
    if (id == 0 && tid == 0)
      ((float*)Cv)[(size_t)M * N] = 0.0f;  // loss scalar
  }
}

// ---------------- Flash attention: LDS-staged K/V, 2-phase pipeline, XCD swizzle --------
__global__ __launch_bounds__(256, 4) void attn_fwd(const u16* __restrict__ Q,
                                                   const u16* __restrict__ Kh,
                                                   const u16* __restrict__ VL,
                                                   u16* __restrict__ X) {
  __shared__ u16 Ks[2][4096];  // 64 keys x 64 d (swizzled)
  __shared__ u16 Vs[2][4096];  // 2 fragment-order sub-blocks (32 keys each, swizzled)

  const int tid = threadIdx.x, lane = tid & 63, w = tid >> 6;
  const int l16 = lane & 15, lhi = lane >> 4;
  const int blk = blockIdx.x;
  const int xcd = blk & 7, wi = blk >> 3;
  const int bh = (xcd << 3) | (wi >> 4);
  const int qt = wi & 15;
  const int b = bh >> 4, h = bh & 15;

  const size_t qrow0 = (size_t)bh * 2048 + qt * 128 + w * 32;
  half8 qf[2][2];
#pragma unroll
  for (int fq = 0; fq < 2; ++fq)
#pragma unroll
    for (int ks = 0; ks < 2; ++ks)
      qf[fq][ks] = *reinterpret_cast<const half8*>(
          &Q[(qrow0 + fq * 16 + l16) * 64 + ks * 32 + lhi * 8]);

  f32x4 o[2][4] = {};
  float mrow[2] = {-1e30f, -1e30f};
  float ssum[2] = {0.0f, 0.0f};

  const u16* Kb = Kh + (size_t)bh * 2048 * 64;
  const u16* VLh = VL + (size_t)bh * 64 * 64 * 32;

#define STAGE_KV(bufidx, tt)                                                      \
  do {                                                                            \
    const int kb0_ = (tt) * 64;                                                   \
    _Pragma("unroll")                                                             \
    for (int ii_ = 0; ii_ < 2; ++ii_) {                                           \
      const int c_ = tid + ii_ * 256;                                             \
      const int r_ = c_ >> 3, cb_ = c_ & 7;                                       \
      gload_lds16(Kb + (size_t)(kb0_ + r_) * 64 + ((cb_ ^ (r_ & 7)) << 3),        \
                  &Ks[bufidx][c_ * 8]);                                           \
      gload_lds16(VLh + (size_t)(tt) * 4096 + c_ * 8, &Vs[bufidx][c_ * 8]);       \
    }                                                                             \
  } while (0)

  STAGE_KV(0, 0);
  __syncthreads();

  for (int t = 0; t < 32; ++t) {
    const int cur = t & 1;
    if (t < 31) STAGE_KV(cur ^ 1, t + 1);  // issue next-tile loads BEFORE compute
    // ---- QK^T from swizzled K in LDS (rows=keys, cols=q) ----
    f32x4 sc[2][4] = {};
    __builtin_amdgcn_s_setprio(1);
#pragma unroll
    for (int fk = 0; fk < 4; ++fk) {
      const int row = fk * 16 + l16;
#pragma unroll
      for (int ks = 0; ks < 2; ++ks) {
        const int off = (row * 64 + ks * 32 + lhi * 8) ^ ((row & 7) << 3);
        const half8 kf = *reinterpret_cast<const half8*>(&Ks[cur][off]);
#pragma unroll
        for (int fq = 0; fq < 2; ++fq) sc[fq][fk] = MFMAH(kf, qf[fq][ks], sc[fq][fk]);
      }
    }
    __builtin_amdgcn_s_setprio(0);
    // ---- defer-max online softmax ----
    float lm[2];
#pragma unroll
    for (int fq = 0; fq < 2; ++fq) {
      float a0 = fmaxf(fmaxf(sc[fq][0][0], sc[fq][0][1]), sc[fq][0][2]);
      float a1 = fmaxf(fmaxf(sc[fq][0][3], sc[fq][1][0]), sc[fq][1][1]);
      float a2 = fmaxf(fmaxf(sc[fq][1][2], sc[fq][1][3]), sc[fq][2][0]);
      float a3 = fmaxf(fmaxf(sc[fq][2][1], sc[fq][2][2]), sc[fq][2][3]);
      float a4 = fmaxf(fmaxf(sc[fq][3][0], sc[fq][3][1]), sc[fq][3][2]);
      float b0 = fmaxf(fmaxf(a0, a1), a2);
      float b1 = fmaxf(fmaxf(a3, a4), sc[fq][3][3]);
      lm[fq] = fmaxf(b0, b1);
    }
    const int trig = (lm[0] > mrow[0] + THR) || (lm[1] > mrow[1] + THR);
    if (__any(trig)) {
#pragma unroll
      for (int fq = 0; fq < 2; ++fq) {
        float rm = lm[fq];
        rm = fmaxf(rm, __shfl_xor(rm, 16));
        rm = fmaxf(rm, __shfl_xor(rm, 32));
        const float nm = fmaxf(mrow[fq], rm);
        const float scl = __builtin_amdgcn_exp2f(mrow[fq] - nm);
        mrow[fq] = nm;
        ssum[fq] *= scl;
        float sb[4];
#pragma unroll
        for (int r = 0; r < 4; ++r) sb[r] = __shfl(scl, lhi * 4 + r);
#pragma unroll
        for (int fd = 0; fd < 4; ++fd)
#pragma unroll
          for (int r = 0; r < 4; ++r) o[fq][fd][r] *= sb[r];
      }
    }
    // ---- exp2 + pack P to fp16 ----
    half8 pa2[2][2];
#pragma unroll
    for (int fq = 0; fq < 2; ++fq) {
      union { half8 v[2]; h2 hh[8]; } uu;
#pragma unroll
      for (int fk = 0; fk < 4; ++fk) {
        const float p0 = __builtin_amdgcn_exp2f(sc[fq][fk][0] - mrow[fq]);
        const float p1 = __builtin_amdgcn_exp2f(sc[fq][fk][1] - mrow[fq]);
        const float p2 = __builtin_amdgcn_exp2f(sc[fq][fk][2] - mrow[fq]);
        const float p3 = __builtin_amdgcn_exp2f(sc[fq][fk][3] - mrow[fq]);
        ssum[fq] += (p0 + p1) + (p2 + p3);
        uu.hh[fk * 2 + 0] = pkrtz(p0, p1);
        uu.hh[fk * 2 + 1] = pkrtz(p2, p3);
      }
      pa2[fq][0] = uu.v[0];
      pa2[fq][1] = uu.v[1];
    }
    // ---- PV from swizzled fragment-order V in LDS ----
    __builtin_amdgcn_s_setprio(1);
#pragma unroll
    for (int fd = 0; fd < 4; ++fd)
#pragma unroll
      for (int ts = 0; ts < 2; ++ts) {
        const int va = (ts * 2048 + (fd * 16 + l16) * 32 + lhi * 8) ^ ((l16 & 7) << 3);
        const half8 vf = *reinterpret_cast<const half8*>(&Vs[cur][va]);
#pragma unroll
        for (int fq = 0; fq < 2; ++fq) o[fq][fd] = MFMAH(pa2[fq][ts], vf, o[fq][fd]);
      }
    __builtin_amdgcn_s_setprio(0);
    __syncthreads();
  }
#undef STAGE_KV

  // epilogue
#pragma unroll
  for (int fq = 0; fq < 2; ++fq) {
    float ss = ssum[fq];
    ss += __shfl_xor(ss, 16);
    ss += __shfl_xor(ss, 32);
    float iv[4];
#pragma unroll
    for (int r = 0; r < 4; ++r) iv[r] = 1.0f / __shfl(ss, lhi * 4 + r);
#pragma unroll
    for (int r = 0; r < 4; ++r) {
      const int q = qt * 128 + w * 32 + fq * 16 + lhi * 4 + r;
#pragma unroll
      for (int fd = 0; fd < 4; ++fd) {
        const int col = h * 64 + fd * 16 + l16;
        X[((size_t)b * 2048 + q) * 1024 + col] = f2h(o[fq][fd][r] * iv[r]);
      }
    }
  }
}

// ---------------- launch ----------------
extern "C" void kernel_launch(void* const* d_in, const int* in_sizes, int n_in,
                              void* d_out, int out_size, void* d_ws, size_t ws_size,
                              hipStream_t stream) {
  const float* q_f  = (const float*)d_in[0];
  const float* k_f  = (const float*)d_in[1];
  const float* v_f  = (const float*)d_in[2];
  const float* Wq_f = (const float*)d_in[4];
  const float* bq   = (const float*)d_in[5];
  const float* Wk_f = (const float*)d_in[6];
  const float* bk   = (const float*)d_in[7];
  const float* Wv_f = (const float*)d_in[8];
  const float* bv   = (const float*)d_in[9];
  const float* Wo_f = (const float*)d_in[10];
  const float* bo   = (const float*)d_in[11];

  const int SZ = 4 * 2048 * 1024;  // 8388608
  const int SW = 1024 * 1024;      // 1048576

  u16* ws = (u16*)d_ws;
  u16* wqb = ws;                 // fp16 weights
  u16* wkb = wqb + SW;
  u16* wvb = wkb + SW;
  u16* wob = wvb + SW;
  u16* Qb  = wob + SW;           // [B,H,S,D], pre-scaled by log2e
  u16* Kb  = Qb + SZ;            // [B,H,S,D]
  u16* VLb = Kb + SZ;            // swizzled fragment-order V
  u16* Xb  = VLb + SZ;           // [B,S,H*D]
  const size_t need_bytes = (size_t)(4 * SZ + 4 * SW) * 2;
  if (ws_size < need_bytes) return;

  conv_w4<<<1024, 256, 0, stream>>>(Wq_f, Wk_f, Wv_f, Wo_f, wqb, wkb, wvb, wob, SW / 8);

  dim3 gg(1024 / 128, 8192 / 128);
  gemm_bt<1, true><<<gg, 256, 0, stream>>>(q_f, wqb, bq, Qb, 8192, 1024, 1024, LOG2E);
  gemm_bt<1, true><<<gg, 256, 0, stream>>>(k_f, wkb, bk, Kb, 8192, 1024, 1024, 1.0f);
  gemm_bt<2, true><<<gg, 256, 0, stream>>>(v_f, wvb, bv, VLb, 8192, 1024, 1024, 1.0f);

  attn_fwd<<<dim3(1024), 256, 0, stream>>>(Qb, Kb, VLb, Xb);

  gemm_bt<0, false><<<gg, 256, 0, stream>>>(Xb, wob, bo, d_out, 8192, 1024, 1024, 1.0f);
}

// Round 11
// 214.769 us; speedup vs baseline: 1.1827x; 1.1383x over previous
//
#include <hip/hip_runtime.h>

typedef unsigned short u16;
typedef _Float16 half8 __attribute__((ext_vector_type(8)));
typedef _Float16 h2 __attribute__((ext_vector_type(2)));
typedef float f32x4 __attribute__((ext_vector_type(4)));
typedef u16 u16x4 __attribute__((ext_vector_type(4)));
typedef u16 u16x8 __attribute__((ext_vector_type(8)));

#define MFMAH(a, b, c) __builtin_amdgcn_mfma_f32_16x16x32_f16(a, b, c, 0, 0, 0)

constexpr float LOG2E = 1.44269504088896f;
constexpr float THR = 12.0f;  // defer-max threshold in log2 units (p <= 2^12, fp16-safe)

__device__ __forceinline__ u16 f2h(float f) {
  _Float16 h = (_Float16)f;
  return __builtin_bit_cast(u16, h);
}
__device__ __forceinline__ h2 pkrtz(float a, float b) {
  return __builtin_bit_cast(h2, __builtin_amdgcn_cvt_pkrtz(a, b));
}
__device__ __forceinline__ void gload_lds16(const void* g, void* l) {
  __builtin_amdgcn_global_load_lds(
      (const __attribute__((address_space(1))) void*)g,
      (__attribute__((address_space(3))) void*)l,
      16, 0, 0);
}

// ---------------- fp32 -> fp16 conversion (weights only) ----------------
__device__ __forceinline__ void conv_block(const float* __restrict__ in,
                                           u16* __restrict__ out, int i) {
  const float4 a = reinterpret_cast<const float4*>(in)[2 * i];
  const float4 b = reinterpret_cast<const float4*>(in)[2 * i + 1];
  u16x8 o;
  o[0] = f2h(a.x); o[1] = f2h(a.y); o[2] = f2h(a.z); o[3] = f2h(a.w);
  o[4] = f2h(b.x); o[5] = f2h(b.y); o[6] = f2h(b.z); o[7] = f2h(b.w);
  reinterpret_cast<u16x8*>(out)[i] = o;
}

__global__ __launch_bounds__(256) void conv_w4(const float* __restrict__ w0,
                                               const float* __restrict__ w1,
                                               const float* __restrict__ w2,
                                               const float* __restrict__ w3,
                                               u16* __restrict__ o0, u16* __restrict__ o1,
                                               u16* __restrict__ o2, u16* __restrict__ o3,
                                               int n8) {
  int i = blockIdx.x * 256 + threadIdx.x;
  const int stride = gridDim.x * 256;
  for (; i < 4 * n8; i += stride) {
    const int sel = i / n8, j = i - sel * n8;
    if (sel == 0) conv_block(w0, o0, j);
    else if (sel == 1) conv_block(w1, o1, j);
    else if (sel == 2) conv_block(w2, o2, j);
    else conv_block(w3, o3, j);
  }
}

// ---------------- merged projection GEMM (Q,K,V in one launch) ----------------
// Grid (8, 64, 3). All dims hardcoded: M=8192, N=1024, K=1024, tile 128x128, BK=32.
// Double-buffered LDS, ONE barrier per K-step: issue next loads early, convert/write
// A late (after MFMA), so a full compute phase hides load latency (T14).
// z=0: Q -> [B,H,S,D] * log2e ; z=1: K -> [B,H,S,D] ; z=2: V -> swizzled frag order.
__global__ __launch_bounds__(256) void proj_gemm(
    const float* __restrict__ Aq, const float* __restrict__ Ak, const float* __restrict__ Avv,
    const u16* __restrict__ Wq, const u16* __restrict__ Wk, const u16* __restrict__ Wv,
    const float* __restrict__ bq, const float* __restrict__ bk, const float* __restrict__ bv,
    u16* __restrict__ Cq, u16* __restrict__ Ck, u16* __restrict__ Cvv) {
  __shared__ u16 As[2][4096];
  __shared__ u16 Bs[2][4096];
  const int tid = threadIdx.x;
  const int lane = tid & 63, l16 = lane & 15, lhi = lane >> 4;
  const int wid = tid >> 6, wm = wid >> 1, wn = wid & 1;
  // XCD-panel colocation: all 8 bx of one (z,by) panel share one XCD (id%8).
  const int id = blockIdx.x + (blockIdx.y << 3) + (blockIdx.z << 9);
  const int xcd = id & 7;
  const int slot = id >> 3;              // 0..191
  const int by = ((slot & 7) << 3) | xcd;  // by % 8 == xcd
  const int rest = slot >> 3;            // 0..23
  const int bx = rest & 7;
  const int z = rest >> 3;               // 0..2
  const int bm0 = by * 128, bn0 = bx * 128;

  const float* Af = (z == 0) ? Aq : ((z == 1) ? Ak : Avv);
  const u16* Bw = (z == 0) ? Wq : ((z == 1) ? Wk : Wv);
  const float* bias = (z == 0) ? bq : ((z == 1) ? bk : bv);
  u16* C = (z == 0) ? Cq : ((z == 1) ? Ck : Cvv);
  const float scale = (z == 0) ? LOG2E : 1.0f;

  const int c0 = tid, c1 = tid + 256;
  const u16* Bg0 = Bw + (size_t)(bn0 + (c0 >> 2)) * 1024 + (c0 & 3) * 8;
  const u16* Bg1 = Bw + (size_t)(bn0 + (c1 >> 2)) * 1024 + (c1 & 3) * 8;
  const float* Ar = Af + (size_t)(bm0 + (tid >> 1)) * 1024 + (tid & 1) * 16;
  u16* AsW0 = &As[0][(tid >> 1) * 32 + (tid & 1) * 16];
  u16* AsW1 = &As[1][(tid >> 1) * 32 + (tid & 1) * 16];

  f32x4 acc[4][4] = {};
  float4 an[4];

#define LOADA(kt)                                            \
  do {                                                       \
    an[0] = *reinterpret_cast<const float4*>(Ar + (kt));     \
    an[1] = *reinterpret_cast<const float4*>(Ar + (kt) + 4); \
    an[2] = *reinterpret_cast<const float4*>(Ar + (kt) + 8); \
    an[3] = *reinterpret_cast<const float4*>(Ar + (kt) + 12);\
  } while (0)
#define STAGEB(buf, kt)                                      \
  do {                                                       \
    gload_lds16(Bg0 + (kt), &Bs[buf][c0 * 8]);               \
    gload_lds16(Bg1 + (kt), &Bs[buf][c1 * 8]);               \
  } while (0)
#define WRITEA(buf)                                          \
  do {                                                       \
    union { u16x8 u; h2 h[4]; } w0_, w1_;                    \
    w0_.h[0] = pkrtz(an[0].x, an[0].y); w0_.h[1] = pkrtz(an[0].z, an[0].w); \
    w0_.h[2] = pkrtz(an[1].x, an[1].y); w0_.h[3] = pkrtz(an[1].z, an[1].w); \
    w1_.h[0] = pkrtz(an[2].x, an[2].y); w1_.h[1] = pkrtz(an[2].z, an[2].w); \
    w1_.h[2] = pkrtz(an[3].x, an[3].y); w1_.h[3] = pkrtz(an[3].z, an[3].w); \
    u16* dst_ = (buf) ? AsW1 : AsW0;                         \
    *reinterpret_cast<u16x8*>(dst_) = w0_.u;                 \
    *reinterpret_cast<u16x8*>(dst_ + 8) = w1_.u;             \
  } while (0)

  LOADA(0);
  STAGEB(0, 0);
  WRITEA(0);
  __syncthreads();

  for (int ki = 0; ki < 32; ++ki) {
    const int cur = ki & 1, nxt = cur ^ 1;
    if (ki < 31) {
      LOADA((ki + 1) * 32);       // issue next A loads (regs) early
      STAGEB(nxt, (ki + 1) * 32); // issue next B gload_lds early
    }
    half8 af[4], bf[4];
#pragma unroll
    for (int f = 0; f < 4; ++f)
      af[f] = *reinterpret_cast<const half8*>(&As[cur][(wm * 64 + f * 16 + l16) * 32 + lhi * 8]);
#pragma unroll
    for (int f = 0; f < 4; ++f)
      bf[f] = *reinterpret_cast<const half8*>(&Bs[cur][(wn * 64 + f * 16 + l16) * 32 + lhi * 8]);
#pragma unroll
    for (int i = 0; i < 4; ++i)
#pragma unroll
      for (int j = 0; j < 4; ++j)
        acc[i][j] = MFMAH(af[i], bf[j], acc[i][j]);
    if (ki < 31) WRITEA(nxt);     // convert+write A late (latency hidden by MFMA)
    __syncthreads();
  }
#undef LOADA
#undef STAGEB
#undef WRITEA

#pragma unroll
  for (int i = 0; i < 4; ++i) {
    const int m0 = bm0 + wm * 64 + i * 16 + lhi * 4;
#pragma unroll
    for (int j = 0; j < 4; ++j) {
      const int n = bn0 + wn * 64 + j * 16 + l16;
      const float bb = bias[n];
      if (z == 2) {
        u16x4 pack;
#pragma unroll
        for (int r = 0; r < 4; ++r) pack[r] = f2h(acc[i][j][r] + bb);
        const int head = (m0 >> 11) * 16 + (n >> 6);
        const int s0 = m0 & 2047;
        const int d = n & 63;
        const int within =
            ((s0 >> 5) & 1) * 2048 + d * 32 + ((s0 >> 2) & 3) * 8 + ((s0 >> 4) & 1) * 4;
        const int sw = within ^ ((d & 7) << 3);  // bank swizzle (matches attn read)
        const size_t idx = (size_t)head * 131072 + (size_t)(s0 >> 6) * 4096 + sw;
        *reinterpret_cast<u16x4*>(&C[idx]) = pack;
      } else {
#pragma unroll
        for (int r = 0; r < 4; ++r) {
          const int m = m0 + r;
          const size_t idx =
              ((size_t)((m >> 11) * 16 + (n >> 6)) * 2048 + (m & 2047)) * 64 + (n & 63);
          C[idx] = f2h((acc[i][j][r] + bb) * scale);
        }
      }
    }
  }
}

// ---------------- output GEMM: X(fp16) @ Wo^T + bo -> f32 out (+ loss scalar) ----------
__global__ __launch_bounds__(256) void out_gemm(const u16* __restrict__ A,
                                                const u16* __restrict__ Bw,
                                                const float* __restrict__ bias,
                                                float* __restrict__ C) {
  __shared__ u16 As[2][4096];
  __shared__ u16 Bs[2][4096];
  const int tid = threadIdx.x;
  const int lane = tid & 63, l16 = lane & 15, lhi = lane >> 4;
  const int wid = tid >> 6, wm = wid >> 1, wn = wid & 1;
  const int id = blockIdx.x + (blockIdx.y << 3);
  const int xcd = id & 7, slot = id >> 3;
  const int by = ((slot & 7) << 3) | xcd;
  const int bx = slot >> 3;
  const int bm0 = by * 128, bn0 = bx * 128;

  const int c0 = tid, c1 = tid + 256;
  const u16* Ag0 = A + (size_t)(bm0 + (c0 >> 2)) * 1024 + (c0 & 3) * 8;
  const u16* Ag1 = A + (size_t)(bm0 + (c1 >> 2)) * 1024 + (c1 & 3) * 8;
  const u16* Bg0 = Bw + (size_t)(bn0 + (c0 >> 2)) * 1024 + (c0 & 3) * 8;
  const u16* Bg1 = Bw + (size_t)(bn0 + (c1 >> 2)) * 1024 + (c1 & 3) * 8;

  f32x4 acc[4][4] = {};

#define STAGE16(buf, kt)                                  \
  do {                                                    \
    gload_lds16(Ag0 + (kt), &As[buf][c0 * 8]);            \
    gload_lds16(Ag1 + (kt), &As[buf][c1 * 8]);            \
    gload_lds16(Bg0 + (kt), &Bs[buf][c0 * 8]);            \
    gload_lds16(Bg1 + (kt), &Bs[buf][c1 * 8]);            \
  } while (0)

  STAGE16(0, 0);
  __syncthreads();
  for (int ki = 0; ki < 32; ++ki) {
    const int cur = ki & 1;
    if (ki < 31) STAGE16(cur ^ 1, (ki + 1) * 32);
    half8 af[4], bf[4];
#pragma unroll
    for (int f = 0; f < 4; ++f)
      af[f] = *reinterpret_cast<const half8*>(&As[cur][(wm * 64 + f * 16 + l16) * 32 + lhi * 8]);
#pragma unroll
    for (int f = 0; f < 4; ++f)
      bf[f] = *reinterpret_cast<const half8*>(&Bs[cur][(wn * 64 + f * 16 + l16) * 32 + lhi * 8]);
#pragma unroll
    for (int i = 0; i < 4; ++i)
#pragma unroll
      for (int j = 0; j < 4; ++j)
        acc[i][j] = MFMAH(af[i], bf[j], acc[i][j]);
    __syncthreads();
  }
#undef STAGE16

#pragma unroll
  for (int i = 0; i < 4; ++i) {
    const int m0 = bm0 + wm * 64 + i * 16 + lhi * 4;
#pragma unroll
    for (int j = 0; j < 4; ++j) {
      const int n = bn0 + wn * 64 + j * 16 + l16;
      const float bb = bias[n];
#pragma unroll
      for (int r = 0; r < 4; ++r)
        C[(size_t)(m0 + r) * 1024 + n] = acc[i][j][r] + bb;
    }
  }
  if (id == 0 && tid == 0) C[(size_t)8192 * 1024] = 0.0f;  // loss scalar
}

// ---------------- Flash attention (unchanged from R10) ----------------
__global__ __launch_bounds__(256, 4) void attn_fwd(const u16* __restrict__ Q,
                                                   const u16* __restrict__ Kh,
                                                   const u16* __restrict__ VL,
                                                   u16* __restrict__ X) {
  __shared__ u16 Ks[2][4096];
  __shared__ u16 Vs[2][4096];

  const int tid = threadIdx.x, lane = tid & 63, w = tid >> 6;
  const int l16 = lane & 15, lhi = lane >> 4;
  const int blk = blockIdx.x;
  const int xcd = blk & 7, wi = blk >> 3;
  const int bh = (xcd << 3) | (wi >> 4);
  const int qt = wi & 15;
  const int b = bh >> 4, h = bh & 15;

  const size_t qrow0 = (size_t)bh * 2048 + qt * 128 + w * 32;
  half8 qf[2][2];
#pragma unroll
  for (int fq = 0; fq < 2; ++fq)
#pragma unroll
    for (int ks = 0; ks < 2; ++ks)
      qf[fq][ks] = *reinterpret_cast<const half8*>(
          &Q[(qrow0 + fq * 16 + l16) * 64 + ks * 32 + lhi * 8]);

  f32x4 o[2][4] = {};
  float mrow[2] = {-1e30f, -1e30f};
  float ssum[2] = {0.0f, 0.0f};

  const u16* Kb = Kh + (size_t)bh * 2048 * 64;
  const u16* VLh = VL + (size_t)bh * 64 * 64 * 32;

#define STAGE_KV(bufidx, tt)                                                      \
  do {                                                                            \
    const int kb0_ = (tt) * 64;                                                   \
    _Pragma("unroll")                                                             \
    for (int ii_ = 0; ii_ < 2; ++ii_) {                                           \
      const int c_ = tid + ii_ * 256;                                             \
      const int r_ = c_ >> 3, cb_ = c_ & 7;                                       \
      gload_lds16(Kb + (size_t)(kb0_ + r_) * 64 + ((cb_ ^ (r_ & 7)) << 3),        \
                  &Ks[bufidx][c_ * 8]);                                           \
      gload_lds16(VLh + (size_t)(tt) * 4096 + c_ * 8, &Vs[bufidx][c_ * 8]);       \
    }                                                                             \
  } while (0)

  STAGE_KV(0, 0);
  __syncthreads();

  for (int t = 0; t < 32; ++t) {
    const int cur = t & 1;
    if (t < 31) STAGE_KV(cur ^ 1, t + 1);
    f32x4 sc[2][4] = {};
    __builtin_amdgcn_s_setprio(1);
#pragma unroll
    for (int fk = 0; fk < 4; ++fk) {
      const int row = fk * 16 + l16;
#pragma unroll
      for (int ks = 0; ks < 2; ++ks) {
        const int off = (row * 64 + ks * 32 + lhi * 8) ^ ((row & 7) << 3);
        const half8 kf = *reinterpret_cast<const half8*>(&Ks[cur][off]);
#pragma unroll
        for (int fq = 0; fq < 2; ++fq) sc[fq][fk] = MFMAH(kf, qf[fq][ks], sc[fq][fk]);
      }
    }
    __builtin_amdgcn_s_setprio(0);
    float lm[2];
#pragma unroll
    for (int fq = 0; fq < 2; ++fq) {
      float a0 = fmaxf(fmaxf(sc[fq][0][0], sc[fq][0][1]), sc[fq][0][2]);
      float a1 = fmaxf(fmaxf(sc[fq][0][3], sc[fq][1][0]), sc[fq][1][1]);
      float a2 = fmaxf(fmaxf(sc[fq][1][2], sc[fq][1][3]), sc[fq][2][0]);
      float a3 = fmaxf(fmaxf(sc[fq][2][1], sc[fq][2][2]), sc[fq][2][3]);
      float a4 = fmaxf(fmaxf(sc[fq][3][0], sc[fq][3][1]), sc[fq][3][2]);
      float b0 = fmaxf(fmaxf(a0, a1), a2);
      float b1 = fmaxf(fmaxf(a3, a4), sc[fq][3][3]);
      lm[fq] = fmaxf(b0, b1);
    }
    const int trig = (lm[0] > mrow[0] + THR) || (lm[1] > mrow[1] + THR);
    if (__any(trig)) {
#pragma unroll
      for (int fq = 0; fq < 2; ++fq) {
        float rm = lm[fq];
        rm = fmaxf(rm, __shfl_xor(rm, 16));
        rm = fmaxf(rm, __shfl_xor(rm, 32));
        const float nm = fmaxf(mrow[fq], rm);
        const float scl = __builtin_amdgcn_exp2f(mrow[fq] - nm);
        mrow[fq] = nm;
        ssum[fq] *= scl;
        float sb[4];
#pragma unroll
        for (int r = 0; r < 4; ++r) sb[r] = __shfl(scl, lhi * 4 + r);
#pragma unroll
        for (int fd = 0; fd < 4; ++fd)
#pragma unroll
          for (int r = 0; r < 4; ++r) o[fq][fd][r] *= sb[r];
      }
    }
    half8 pa2[2][2];
#pragma unroll
    for (int fq = 0; fq < 2; ++fq) {
      union { half8 v[2]; h2 hh[8]; } uu;
#pragma unroll
      for (int fk = 0; fk < 4; ++fk) {
        const float p0 = __builtin_amdgcn_exp2f(sc[fq][fk][0] - mrow[fq]);
        const float p1 = __builtin_amdgcn_exp2f(sc[fq][fk][1] - mrow[fq]);
        const float p2 = __builtin_amdgcn_exp2f(sc[fq][fk][2] - mrow[fq]);
        const float p3 = __builtin_amdgcn_exp2f(sc[fq][fk][3] - mrow[fq]);
        ssum[fq] += (p0 + p1) + (p2 + p3);
        uu.hh[fk * 2 + 0] = pkrtz(p0, p1);
        uu.hh[fk * 2 + 1] = pkrtz(p2, p3);
      }
      pa2[fq][0] = uu.v[0];
      pa2[fq][1] = uu.v[1];
    }
    __builtin_amdgcn_s_setprio(1);
#pragma unroll
    for (int fd = 0; fd < 4; ++fd)
#pragma unroll
      for (int ts = 0; ts < 2; ++ts) {
        const int va = (ts * 2048 + (fd * 16 + l16) * 32 + lhi * 8) ^ ((l16 & 7) << 3);
        const half8 vf = *reinterpret_cast<const half8*>(&Vs[cur][va]);
#pragma unroll
        for (int fq = 0; fq < 2; ++fq) o[fq][fd] = MFMAH(pa2[fq][ts], vf, o[fq][fd]);
      }
    __builtin_amdgcn_s_setprio(0);
    __syncthreads();
  }
#undef STAGE_KV

#pragma unroll
  for (int fq = 0; fq < 2; ++fq) {
    float ss = ssum[fq];
    ss += __shfl_xor(ss, 16);
    ss += __shfl_xor(ss, 32);
    float iv[4];
#pragma unroll
    for (int r = 0; r < 4; ++r) iv[r] = 1.0f / __shfl(ss, lhi * 4 + r);
#pragma unroll
    for (int r = 0; r < 4; ++r) {
      const int q = qt * 128 + w * 32 + fq * 16 + lhi * 4 + r;
#pragma unroll
      for (int fd = 0; fd < 4; ++fd) {
        const int col = h * 64 + fd * 16 + l16;
        X[((size_t)b * 2048 + q) * 1024 + col] = f2h(o[fq][fd][r] * iv[r]);
      }
    }
  }
}

// ---------------- launch ----------------
extern "C" void kernel_launch(void* const* d_in, const int* in_sizes, int n_in,
                              void* d_out, int out_size, void* d_ws, size_t ws_size,
                              hipStream_t stream) {
  const float* q_f  = (const float*)d_in[0];
  const float* k_f  = (const float*)d_in[1];
  const float* v_f  = (const float*)d_in[2];
  const float* Wq_f = (const float*)d_in[4];
  const float* bq   = (const float*)d_in[5];
  const float* Wk_f = (const float*)d_in[6];
  const float* bk   = (const float*)d_in[7];
  const float* Wv_f = (const float*)d_in[8];
  const float* bv   = (const float*)d_in[9];
  const float* Wo_f = (const float*)d_in[10];
  const float* bo   = (const float*)d_in[11];

  const int SZ = 4 * 2048 * 1024;  // 8388608
  const int SW = 1024 * 1024;      // 1048576

  u16* ws = (u16*)d_ws;
  u16* wqb = ws;                 // fp16 weights
  u16* wkb = wqb + SW;
  u16* wvb = wkb + SW;
  u16* wob = wvb + SW;
  u16* Qb  = wob + SW;           // [B,H,S,D], pre-scaled by log2e
  u16* Kb  = Qb + SZ;            // [B,H,S,D]
  u16* VLb = Kb + SZ;            // swizzled fragment-order V
  u16* Xb  = VLb + SZ;           // [B,S,H*D]
  const size_t need_bytes = (size_t)(4 * SZ + 4 * SW) * 2;
  if (ws_size < need_bytes) return;

  conv_w4<<<1024, 256, 0, stream>>>(Wq_f, Wk_f, Wv_f, Wo_f, wqb, wkb, wvb, wob, SW / 8);

  proj_gemm<<<dim3(8, 64, 3), 256, 0, stream>>>(q_f, k_f, v_f, wqb, wkb, wvb,
                                                bq, bk, bv, Qb, Kb, VLb);

  attn_fwd<<<dim3(1024), 256, 0, stream>>>(Qb, Kb, VLb, Xb);

  out_gemm<<<dim3(8, 64), 256, 0, stream>>>(Xb, wob, bo, (float*)d_out);
}

// Round 12
// 212.138 us; speedup vs baseline: 1.1974x; 1.0124x over previous
//
#include <hip/hip_runtime.h>

typedef unsigned short u16;
typedef _Float16 half8 __attribute__((ext_vector_type(8)));
typedef _Float16 h2 __attribute__((ext_vector_type(2)));
typedef float f32x4 __attribute__((ext_vector_type(4)));
typedef u16 u16x4 __attribute__((ext_vector_type(4)));
typedef u16 u16x8 __attribute__((ext_vector_type(8)));

#define MFMAH(a, b, c) __builtin_amdgcn_mfma_f32_16x16x32_f16(a, b, c, 0, 0, 0)

constexpr float LOG2E = 1.44269504088896f;
constexpr float THR = 12.0f;  // defer-max threshold in log2 units (p <= 2^12, fp16-safe)

__device__ __forceinline__ u16 f2h(float f) {
  _Float16 h = (_Float16)f;
  return __builtin_bit_cast(u16, h);
}
__device__ __forceinline__ h2 pkrtz(float a, float b) {
  return __builtin_bit_cast(h2, __builtin_amdgcn_cvt_pkrtz(a, b));
}
__device__ __forceinline__ void gload_lds16(const void* g, void* l) {
  __builtin_amdgcn_global_load_lds(
      (const __attribute__((address_space(1))) void*)g,
      (__attribute__((address_space(3))) void*)l,
      16, 0, 0);
}

// LDS tile swizzle for [128][32]-u16 tiles (64B rows): quarter q' = q ^ ((row>>1)&3).
// Spreads a 16-lane phase over all 8 16B slots per 128B bank-cycle (2-way = floor).
__device__ __forceinline__ int swz(int row, int q) { return row * 32 + ((q ^ ((row >> 1) & 3)) << 3); }

// ---------------- fp32 -> fp16 conversion (weights only) ----------------
__device__ __forceinline__ void conv_block(const float* __restrict__ in,
                                           u16* __restrict__ out, int i) {
  const float4 a = reinterpret_cast<const float4*>(in)[2 * i];
  const float4 b = reinterpret_cast<const float4*>(in)[2 * i + 1];
  u16x8 o;
  o[0] = f2h(a.x); o[1] = f2h(a.y); o[2] = f2h(a.z); o[3] = f2h(a.w);
  o[4] = f2h(b.x); o[5] = f2h(b.y); o[6] = f2h(b.z); o[7] = f2h(b.w);
  reinterpret_cast<u16x8*>(out)[i] = o;
}

__global__ __launch_bounds__(256) void conv_w4(const float* __restrict__ w0,
                                               const float* __restrict__ w1,
                                               const float* __restrict__ w2,
                                               const float* __restrict__ w3,
                                               u16* __restrict__ o0, u16* __restrict__ o1,
                                               u16* __restrict__ o2, u16* __restrict__ o3,
                                               int n8) {
  int i = blockIdx.x * 256 + threadIdx.x;
  const int stride = gridDim.x * 256;
  for (; i < 4 * n8; i += stride) {
    const int sel = i / n8, j = i - sel * n8;
    if (sel == 0) conv_block(w0, o0, j);
    else if (sel == 1) conv_block(w1, o1, j);
    else if (sel == 2) conv_block(w2, o2, j);
    else conv_block(w3, o3, j);
  }
}

// ---------------- merged projection GEMM (Q,K,V in one launch) ----------------
// Grid (8, 64, 3); M=8192, N=1024, K=1024, tile 128x128, BK=32, double-buffered,
// one barrier per K-step. LDS tiles swizzled per swz() on BOTH write and read sides;
// B's swizzle is applied by permuting the GLOBAL source column (LDS dest linear).
__global__ __launch_bounds__(256) void proj_gemm(
    const float* __restrict__ Aq, const float* __restrict__ Ak, const float* __restrict__ Avv,
    const u16* __restrict__ Wq, const u16* __restrict__ Wk, const u16* __restrict__ Wv,
    const float* __restrict__ bq, const float* __restrict__ bk, const float* __restrict__ bv,
    u16* __restrict__ Cq, u16* __restrict__ Ck, u16* __restrict__ Cvv) {
  __shared__ u16 As[2][4096];
  __shared__ u16 Bs[2][4096];
  const int tid = threadIdx.x;
  const int lane = tid & 63, l16 = lane & 15, lhi = lane >> 4;
  const int wid = tid >> 6, wm = wid >> 1, wn = wid & 1;
  // XCD-panel colocation: all 8 bx of one (z,by) panel share one XCD (id%8).
  const int id = blockIdx.x + (blockIdx.y << 3) + (blockIdx.z << 9);
  const int xcd = id & 7;
  const int slot = id >> 3;
  const int by = ((slot & 7) << 3) | xcd;  // by % 8 == xcd
  const int rest = slot >> 3;
  const int bx = rest & 7;
  const int z = rest >> 3;
  const int bm0 = by * 128, bn0 = bx * 128;

  const float* Af = (z == 0) ? Aq : ((z == 1) ? Ak : Avv);
  const u16* Bw = (z == 0) ? Wq : ((z == 1) ? Wk : Wv);
  const float* bias = (z == 0) ? bq : ((z == 1) ? bk : bv);
  u16* C = (z == 0) ? Cq : ((z == 1) ? Ck : Cvv);
  const float scale = (z == 0) ? LOG2E : 1.0f;

  // B staging: chunk c -> LDS linear c*8 u16 (row c>>2, quarter c&3); global source
  // column pre-swizzled so LDS holds the swizzled layout.
  const int c0 = tid, c1 = tid + 256;
  const u16* Bg0 = Bw + (size_t)(bn0 + (c0 >> 2)) * 1024 + (((c0 & 3) ^ ((c0 >> 3) & 3)) << 3);
  const u16* Bg1 = Bw + (size_t)(bn0 + (c1 >> 2)) * 1024 + (((c1 & 3) ^ ((c1 >> 3) & 3)) << 3);
  // A staging: thread owns rows (tid>>2) and (tid>>2)+64, 8 f32 cols at (tid&3)*8.
  const int arow = tid >> 2, aq = tid & 3;
  const float* Ar = Af + (size_t)(bm0 + arow) * 1024 + aq * 8;
  const int awoff = swz(arow, aq);  // same XOR for row and row+64 ((row>>1)&3 identical)

  f32x4 acc[4][4] = {};
  float4 an[4];

#define LOADA(kt)                                                          \
  do {                                                                     \
    an[0] = *reinterpret_cast<const float4*>(Ar + (kt));                   \
    an[1] = *reinterpret_cast<const float4*>(Ar + (kt) + 4);               \
    an[2] = *reinterpret_cast<const float4*>(Ar + (kt) + 64 * 1024);       \
    an[3] = *reinterpret_cast<const float4*>(Ar + (kt) + 64 * 1024 + 4);   \
  } while (0)
#define STAGEB(buf, kt)                                                    \
  do {                                                                     \
    gload_lds16(Bg0 + (kt), &Bs[buf][c0 * 8]);                             \
    gload_lds16(Bg1 + (kt), &Bs[buf][c1 * 8]);                             \
  } while (0)
#define WRITEA(buf)                                                        \
  do {                                                                     \
    union { u16x8 u; h2 h[4]; } w0_, w1_;                                  \
    w0_.h[0] = pkrtz(an[0].x, an[0].y); w0_.h[1] = pkrtz(an[0].z, an[0].w);\
    w0_.h[2] = pkrtz(an[1].x, an[1].y); w0_.h[3] = pkrtz(an[1].z, an[1].w);\
    w1_.h[0] = pkrtz(an[2].x, an[2].y); w1_.h[1] = pkrtz(an[2].z, an[2].w);\
    w1_.h[2] = pkrtz(an[3].x, an[3].y); w1_.h[3] = pkrtz(an[3].z, an[3].w);\
    u16* dst_ = &As[buf][awoff];                                           \
    *reinterpret_cast<u16x8*>(dst_) = w0_.u;                               \
    *reinterpret_cast<u16x8*>(dst_ + 64 * 32) = w1_.u;                     \
  } while (0)

  LOADA(0);
  STAGEB(0, 0);
  WRITEA(0);
  __syncthreads();

  for (int ki = 0; ki < 32; ++ki) {
    const int cur = ki & 1, nxt = cur ^ 1;
    if (ki < 31) {
      LOADA((ki + 1) * 32);
      STAGEB(nxt, (ki + 1) * 32);
    }
    half8 af[4], bf[4];
#pragma unroll
    for (int f = 0; f < 4; ++f)
      af[f] = *reinterpret_cast<const half8*>(&As[cur][swz(wm * 64 + f * 16 + l16, lhi)]);
#pragma unroll
    for (int f = 0; f < 4; ++f)
      bf[f] = *reinterpret_cast<const half8*>(&Bs[cur][swz(wn * 64 + f * 16 + l16, lhi)]);
#pragma unroll
    for (int i = 0; i < 4; ++i)
#pragma unroll
      for (int j = 0; j < 4; ++j)
        acc[i][j] = MFMAH(af[i], bf[j], acc[i][j]);
    if (ki < 31) WRITEA(nxt);
    __syncthreads();
  }
#undef LOADA
#undef STAGEB
#undef WRITEA

#pragma unroll
  for (int i = 0; i < 4; ++i) {
    const int m0 = bm0 + wm * 64 + i * 16 + lhi * 4;
#pragma unroll
    for (int j = 0; j < 4; ++j) {
      const int n = bn0 + wn * 64 + j * 16 + l16;
      const float bb = bias[n];
      if (z == 2) {
        u16x4 pack;
#pragma unroll
        for (int r = 0; r < 4; ++r) pack[r] = f2h(acc[i][j][r] + bb);
        const int head = (m0 >> 11) * 16 + (n >> 6);
        const int s0 = m0 & 2047;
        const int d = n & 63;
        const int within =
            ((s0 >> 5) & 1) * 2048 + d * 32 + ((s0 >> 2) & 3) * 8 + ((s0 >> 4) & 1) * 4;
        const int sw = within ^ ((d & 7) << 3);  // bank swizzle (matches attn read)
        const size_t idx = (size_t)head * 131072 + (size_t)(s0 >> 6) * 4096 + sw;
        *reinterpret_cast<u16x4*>(&C[idx]) = pack;
      } else {
#pragma unroll
        for (int r = 0; r < 4; ++r) {
          const int m = m0 + r;
          const size_t idx =
              ((size_t)((m >> 11) * 16 + (n >> 6)) * 2048 + (m & 2047)) * 64 + (n & 63);
          C[idx] = f2h((acc[i][j][r] + bb) * scale);
        }
      }
    }
  }
}

// ---------------- output GEMM: X(fp16) @ Wo^T + bo -> f32 out (+ loss scalar) ----------
__global__ __launch_bounds__(256) void out_gemm(const u16* __restrict__ A,
                                                const u16* __restrict__ Bw,
                                                const float* __restrict__ bias,
                                                float* __restrict__ C) {
  __shared__ u16 As[2][4096];
  __shared__ u16 Bs[2][4096];
  const int tid = threadIdx.x;
  const int lane = tid & 63, l16 = lane & 15, lhi = lane >> 4;
  const int wid = tid >> 6, wm = wid >> 1, wn = wid & 1;
  const int id = blockIdx.x + (blockIdx.y << 3);
  const int xcd = id & 7, slot = id >> 3;
  const int by = ((slot & 7) << 3) | xcd;
  const int bx = slot >> 3;
  const int bm0 = by * 128, bn0 = bx * 128;

  const int c0 = tid, c1 = tid + 256;
  // pre-swizzled global source columns (LDS dest linear -> LDS holds swizzled layout)
  const u16* Ag0 = A + (size_t)(bm0 + (c0 >> 2)) * 1024 + (((c0 & 3) ^ ((c0 >> 3) & 3)) << 3);
  const u16* Ag1 = A + (size_t)(bm0 + (c1 >> 2)) * 1024 + (((c1 & 3) ^ ((c1 >> 3) & 3)) << 3);
  const u16* Bg0 = Bw + (size_t)(bn0 + (c0 >> 2)) * 1024 + (((c0 & 3) ^ ((c0 >> 3) & 3)) << 3);
  const u16* Bg1 = Bw + (size_t)(bn0 + (c1 >> 2)) * 1024 + (((c1 & 3) ^ ((c1 >> 3) & 3)) << 3);

  f32x4 acc[4][4] = {};

#define STAGE16(buf, kt)                                  \
  do {                                                    \
    gload_lds16(Ag0 + (kt), &As[buf][c0 * 8]);            \
    gload_lds16(Ag1 + (kt), &As[buf][c1 * 8]);            \
    gload_lds16(Bg0 + (kt), &Bs[buf][c0 * 8]);            \
    gload_lds16(Bg1 + (kt), &Bs[buf][c1 * 8]);            \
  } while (0)

  STAGE16(0, 0);
  __syncthreads();
  for (int ki = 0; ki < 32; ++ki) {
    const int cur = ki & 1;
    if (ki < 31) STAGE16(cur ^ 1, (ki + 1) * 32);
    half8 af[4], bf[4];
#pragma unroll
    for (int f = 0; f < 4; ++f)
      af[f] = *reinterpret_cast<const half8*>(&As[cur][swz(wm * 64 + f * 16 + l16, lhi)]);
#pragma unroll
    for (int f = 0; f < 4; ++f)
      bf[f] = *reinterpret_cast<const half8*>(&Bs[cur][swz(wn * 64 + f * 16 + l16, lhi)]);
#pragma unroll
    for (int i = 0; i < 4; ++i)
#pragma unroll
      for (int j = 0; j < 4; ++j)
        acc[i][j] = MFMAH(af[i], bf[j], acc[i][j]);
    __syncthreads();
  }
#undef STAGE16

#pragma unroll
  for (int i = 0; i < 4; ++i) {
    const int m0 = bm0 + wm * 64 + i * 16 + lhi * 4;
#pragma unroll
    for (int j = 0; j < 4; ++j) {
      const int n = bn0 + wn * 64 + j * 16 + l16;
      const float bb = bias[n];
#pragma unroll
      for (int r = 0; r < 4; ++r)
        C[(size_t)(m0 + r) * 1024 + n] = acc[i][j][r] + bb;
    }
  }
  if (id == 0 && tid == 0) C[(size_t)8192 * 1024] = 0.0f;  // loss scalar
}

// ---------------- Flash attention (unchanged) ----------------
__global__ __launch_bounds__(256, 4) void attn_fwd(const u16* __restrict__ Q,
                                                   const u16* __restrict__ Kh,
                                                   const u16* __restrict__ VL,
                                                   u16* __restrict__ X) {
  __shared__ u16 Ks[2][4096];
  __shared__ u16 Vs[2][4096];

  const int tid = threadIdx.x, lane = tid & 63, w = tid >> 6;
  const int l16 = lane & 15, lhi = lane >> 4;
  const int blk = blockIdx.x;
  const int xcd = blk & 7, wi = blk >> 3;
  const int bh = (xcd << 3) | (wi >> 4);
  const int qt = wi & 15;
  const int b = bh >> 4, h = bh & 15;

  const size_t qrow0 = (size_t)bh * 2048 + qt * 128 + w * 32;
  half8 qf[2][2];
#pragma unroll
  for (int fq = 0; fq < 2; ++fq)
#pragma unroll
    for (int ks = 0; ks < 2; ++ks)
      qf[fq][ks] = *reinterpret_cast<const half8*>(
          &Q[(qrow0 + fq * 16 + l16) * 64 + ks * 32 + lhi * 8]);

  f32x4 o[2][4] = {};
  float mrow[2] = {-1e30f, -1e30f};
  float ssum[2] = {0.0f, 0.0f};

  const u16* Kb = Kh + (size_t)bh * 2048 * 64;
  const u16* VLh = VL + (size_t)bh * 64 * 64 * 32;

#define STAGE_KV(bufidx, tt)                                                      \
  do {                                                                            \
    const int kb0_ = (tt) * 64;                                                   \
    _Pragma("unroll")                                                             \
    for (int ii_ = 0; ii_ < 2; ++ii_) {                                           \
      const int c_ = tid + ii_ * 256;                                             \
      const int r_ = c_ >> 3, cb_ = c_ & 7;                                       \
      gload_lds16(Kb + (size_t)(kb0_ + r_) * 64 + ((cb_ ^ (r_ & 7)) << 3),        \
                  &Ks[bufidx][c_ * 8]);                                           \
      gload_lds16(VLh + (size_t)(tt) * 4096 + c_ * 8, &Vs[bufidx][c_ * 8]);       \
    }                                                                             \
  } while (0)

  STAGE_KV(0, 0);
  __syncthreads();

  for (int t = 0; t < 32; ++t) {
    const int cur = t & 1;
    if (t < 31) STAGE_KV(cur ^ 1, t + 1);
    f32x4 sc[2][4] = {};
    __builtin_amdgcn_s_setprio(1);
#pragma unroll
    for (int fk = 0; fk < 4; ++fk) {
      const int row = fk * 16 + l16;
#pragma unroll
      for (int ks = 0; ks < 2; ++ks) {
        const int off = (row * 64 + ks * 32 + lhi * 8) ^ ((row & 7) << 3);
        const half8 kf = *reinterpret_cast<const half8*>(&Ks[cur][off]);
#pragma unroll
        for (int fq = 0; fq < 2; ++fq) sc[fq][fk] = MFMAH(kf, qf[fq][ks], sc[fq][fk]);
      }
    }
    __builtin_amdgcn_s_setprio(0);
    float lm[2];
#pragma unroll
    for (int fq = 0; fq < 2; ++fq) {
      float a0 = fmaxf(fmaxf(sc[fq][0][0], sc[fq][0][1]), sc[fq][0][2]);
      float a1 = fmaxf(fmaxf(sc[fq][0][3], sc[fq][1][0]), sc[fq][1][1]);
      float a2 = fmaxf(fmaxf(sc[fq][1][2], sc[fq][1][3]), sc[fq][2][0]);
      float a3 = fmaxf(fmaxf(sc[fq][2][1], sc[fq][2][2]), sc[fq][2][3]);
      float a4 = fmaxf(fmaxf(sc[fq][3][0], sc[fq][3][1]), sc[fq][3][2]);
      float b0 = fmaxf(fmaxf(a0, a1), a2);
      float b1 = fmaxf(fmaxf(a3, a4), sc[fq][3][3]);
      lm[fq] = fmaxf(b0, b1);
    }
    const int trig = (lm[0] > mrow[0] + THR) || (lm[1] > mrow[1] + THR);
    if (__any(trig)) {
#pragma unroll
      for (int fq = 0; fq < 2; ++fq) {
        float rm = lm[fq];
        rm = fmaxf(rm, __shfl_xor(rm, 16));
        rm = fmaxf(rm, __shfl_xor(rm, 32));
        const float nm = fmaxf(mrow[fq], rm);
        const float scl = __builtin_amdgcn_exp2f(mrow[fq] - nm);
        mrow[fq] = nm;
        ssum[fq] *= scl;
        float sb[4];
#pragma unroll
        for (int r = 0; r < 4; ++r) sb[r] = __shfl(scl, lhi * 4 + r);
#pragma unroll
        for (int fd = 0; fd < 4; ++fd)
#pragma unroll
          for (int r = 0; r < 4; ++r) o[fq][fd][r] *= sb[r];
      }
    }
    half8 pa2[2][2];
#pragma unroll
    for (int fq = 0; fq < 2; ++fq) {
      union { half8 v[2]; h2 hh[8]; } uu;
#pragma unroll
      for (int fk = 0; fk < 4; ++fk) {
        const float p0 = __builtin_amdgcn_exp2f(sc[fq][fk][0] - mrow[fq]);
        const float p1 = __builtin_amdgcn_exp2f(sc[fq][fk][1] - mrow[fq]);
        const float p2 = __builtin_amdgcn_exp2f(sc[fq][fk][2] - mrow[fq]);
        const float p3 = __builtin_amdgcn_exp2f(sc[fq][fk][3] - mrow[fq]);
        ssum[fq] += (p0 + p1) + (p2 + p3);
        uu.hh[fk * 2 + 0] = pkrtz(p0, p1);
        uu.hh[fk * 2 + 1] = pkrtz(p2, p3);
      }
      pa2[fq][0] = uu.v[0];
      pa2[fq][1] = uu.v[1];
    }
    __builtin_amdgcn_s_setprio(1);
#pragma unroll
    for (int fd = 0; fd < 4; ++fd)
#pragma unroll
      for (int ts = 0; ts < 2; ++ts) {
        const int va = (ts * 2048 + (fd * 16 + l16) * 32 + lhi * 8) ^ ((l16 & 7) << 3);
        const half8 vf = *reinterpret_cast<const half8*>(&Vs[cur][va]);
#pragma unroll
        for (int fq = 0; fq < 2; ++fq) o[fq][fd] = MFMAH(pa2[fq][ts], vf, o[fq][fd]);
      }
    __builtin_amdgcn_s_setprio(0);
    __syncthreads();
  }
#undef STAGE_KV

#pragma unroll
  for (int fq = 0; fq < 2; ++fq) {
    float ss = ssum[fq];
    ss += __shfl_xor(ss, 16);
    ss += __shfl_xor(ss, 32);
    float iv[4];
#pragma unroll
    for (int r = 0; r < 4; ++r) iv[r] = 1.0f / __shfl(ss, lhi * 4 + r);
#pragma unroll
    for (int r = 0; r < 4; ++r) {
      const int q = qt * 128 + w * 32 + fq * 16 + lhi * 4 + r;
#pragma unroll
      for (int fd = 0; fd < 4; ++fd) {
        const int col = h * 64 + fd * 16 + l16;
        X[((size_t)b * 2048 + q) * 1024 + col] = f2h(o[fq][fd][r] * iv[r]);
      }
    }
  }
}

// ---------------- launch ----------------
extern "C" void kernel_launch(void* const* d_in, const int* in_sizes, int n_in,
                              void* d_out, int out_size, void* d_ws, size_t ws_size,
                              hipStream_t stream) {
  const float* q_f  = (const float*)d_in[0];
  const float* k_f  = (const float*)d_in[1];
  const float* v_f  = (const float*)d_in[2];
  const float* Wq_f = (const float*)d_in[4];
  const float* bq   = (const float*)d_in[5];
  const float* Wk_f = (const float*)d_in[6];
  const float* bk   = (const float*)d_in[7];
  const float* Wv_f = (const float*)d_in[8];
  const float* bv   = (const float*)d_in[9];
  const float* Wo_f = (const float*)d_in[10];
  const float* bo   = (const float*)d_in[11];

  const int SZ = 4 * 2048 * 1024;  // 8388608
  const int SW = 1024 * 1024;      // 1048576

  u16* ws = (u16*)d_ws;
  u16* wqb = ws;                 // fp16 weights
  u16* wkb = wqb + SW;
  u16* wvb = wkb + SW;
  u16* wob = wvb + SW;
  u16* Qb  = wob + SW;           // [B,H,S,D], pre-scaled by log2e
  u16* Kb  = Qb + SZ;            // [B,H,S,D]
  u16* VLb = Kb + SZ;            // swizzled fragment-order V
  u16* Xb  = VLb + SZ;           // [B,S,H*D]
  const size_t need_bytes = (size_t)(4 * SZ + 4 * SW) * 2;
  if (ws_size < need_bytes) return;

  conv_w4<<<1024, 256, 0, stream>>>(Wq_f, Wk_f, Wv_f, Wo_f, wqb, wkb, wvb, wob, SW / 8);

  proj_gemm<<<dim3(8, 64, 3), 256, 0, stream>>>(q_f, k_f, v_f, wqb, wkb, wvb,
                                                bq, bk, bv, Qb, Kb, VLb);

  attn_fwd<<<dim3(1024), 256, 0, stream>>>(Qb, Kb, VLb, Xb);

  out_gemm<<<dim3(8, 64), 256, 0, stream>>>(Xb, wob, bo, (float*)d_out);
}